// Round 2
// baseline (430.152 us; speedup 1.0000x reference)
//
#include <hip/hip_runtime.h>
#include <hip/hip_bf16.h>

// FirstHitProjector: V_logits (B=4, C=3, K=128, H=256, W=256) f32.
// Per pixel: first depth k where argmax_c != 0; class + softmax probs there
// (or k=K-1 / BG when never hit — note at a never-hit pixel argmax at K-1 is
// 0 anyway, so "last read k" gives the right class AND the right probs).
//
// argmax(softmax)==argmax(logits) -> softmax only at the ONE selected depth.
// Hit prob per k is 2/3 -> wave exits after ~5 iterations; ~16 MB of the
// 403 MB input is touched. Kernel is latency-bound (~10 us); the bench's
// 429 us is dominated by harness poison-fills (top-5 rocprof dispatches are
// all fillBufferAligned @ ~250 us, 1.6 GB each).
//
// This round: 2 pixels/thread via float2 — half the waves, half the memory
// instructions, same bytes. A/B to establish the harness-overhead floor.

constexpr int Bn = 4;
constexpr int Cn = 3;
constexpr int Kn = 128;
constexpr int Hn = 256;
constexpr int Wn = 256;
constexpr int HW = Hn * Wn;            // 65536
constexpr int NPIX = Bn * HW;          // 262144
constexpr int NTHREADS = NPIX / 2;     // 131072, 2 pixels per thread

__global__ __launch_bounds__(256) void first_hit_kernel(
    const float* __restrict__ V, float* __restrict__ out) {
    int tid = blockIdx.x * blockDim.x + threadIdx.x;
    if (tid >= NTHREADS) return;

    int pix = tid * 2;                  // first of the pixel pair (same b, consecutive w)
    int b   = pix >> 16;                // / HW
    int hw  = pix & (HW - 1);

    const size_t strideC = (size_t)Kn * HW;   // 8388608 elems
    const float* base = V + (size_t)b * Cn * strideC + (size_t)hw;
    // float2 view: pixel pair is contiguous in w, 8B-aligned (hw even)
    const float2* p0 = (const float2*)(base);                 // class 0
    const float2* p1 = (const float2*)(base + strideC);       // class 1
    const float2* p2 = (const float2*)(base + 2 * strideC);   // class 2
    constexpr size_t K2 = HW / 2;            // k-stride in float2 units

    bool d0 = false, d1 = false;
    float y00 = 0.f, y01 = 0.f, y02 = 0.f;   // selected logits, pixel 0
    float y10 = 0.f, y11 = 0.f, y12 = 0.f;   // selected logits, pixel 1

    #pragma unroll 1
    for (int k = 0; k < Kn; ++k) {
        size_t off = (size_t)k * K2;
        float2 a0 = p0[off];
        float2 a1 = p1[off];
        float2 a2 = p2[off];
        if (!d0) {
            y00 = a0.x; y01 = a1.x; y02 = a2.x;
            d0 = (a1.x > a0.x) || (a2.x > a0.x);
        }
        if (!d1) {
            y10 = a0.y; y11 = a1.y; y12 = a2.y;
            d1 = (a1.y > a0.y) || (a2.y > a0.y);
        }
        if (d0 && d1) break;
        // if the loop exhausts, y holds k=K-1 values; a never-hit pixel has
        // argmax 0 there, matching the reference's BG class + probs at K-1.
    }

    // pixel 0: class + softmax
    int   c0 = 0;  float m0 = y00;
    if (y01 > m0) { c0 = 1; m0 = y01; }
    if (y02 > m0) { c0 = 2; m0 = y02; }
    float e00 = __expf(y00 - m0), e01 = __expf(y01 - m0), e02 = __expf(y02 - m0);
    float inv0 = 1.0f / (e00 + e01 + e02);

    // pixel 1
    int   c1 = 0;  float m1 = y10;
    if (y11 > m1) { c1 = 1; m1 = y11; }
    if (y12 > m1) { c1 = 2; m1 = y12; }
    float e10 = __expf(y10 - m1), e11 = __expf(y11 - m1), e12 = __expf(y12 - m1);
    float inv1 = 1.0f / (e10 + e11 + e12);

    // outputs: [class: NPIX floats][probs: (B,C,H,W) floats] — float2 stores
    ((float2*)out)[tid] = make_float2((float)c0, (float)c1);

    float* probs = out + NPIX;
    size_t pbase = (size_t)b * Cn * HW + (size_t)hw;
    ((float2*)(probs + pbase))[0]          = make_float2(e00 * inv0, e10 * inv1);
    ((float2*)(probs + pbase + HW))[0]     = make_float2(e01 * inv0, e11 * inv1);
    ((float2*)(probs + pbase + 2 * HW))[0] = make_float2(e02 * inv0, e12 * inv1);
}

extern "C" void kernel_launch(void* const* d_in, const int* in_sizes, int n_in,
                              void* d_out, int out_size, void* d_ws, size_t ws_size,
                              hipStream_t stream) {
    const float* V = (const float*)d_in[0];
    float* out = (float*)d_out;
    int threads = 256;
    int blocks = (NTHREADS + threads - 1) / threads;   // 512
    first_hit_kernel<<<blocks, threads, 0, stream>>>(V, out);
}